// Round 5
// baseline (708.599 us; speedup 1.0000x reference)
//
#include <hip/hip_runtime.h>
#include <hip/hip_bf16.h>
#include <math.h>

#define N_NODES 20000
#define EMB 128
#define HID 64
#define RELS 8
#define CLS 16
#define N_EDGES 640000
#define NEG 0.2f
#define NKEYS (N_NODES * RELS)
#define SCAN_CHUNK 1024
#define SCAN_NBLK ((NKEYS + SCAN_CHUNK - 1) / SCAN_CHUNK)  // 157

typedef unsigned short ushort_t;
typedef __attribute__((ext_vector_type(8))) short bf16x8;
typedef __attribute__((ext_vector_type(4))) float f32x4;

__device__ __forceinline__ float b2f(ushort_t u) {
    return __uint_as_float(((unsigned int)u) << 16);
}
__device__ __forceinline__ ushort_t f2b(float f) {
    __hip_bfloat16 h = __float2bfloat16(f);
    return *reinterpret_cast<ushort_t*>(&h);
}

// ---------------- f32 -> bf16 conversion (vectorized) ----------------
__global__ __launch_bounds__(256) void k_cvt(const float* __restrict__ in, ushort_t* __restrict__ outp, int n4) {
    int i = blockIdx.x * blockDim.x + threadIdx.x;
    if (i >= n4) return;
    float4 v = *(const float4*)&in[(size_t)i * 4];
    ushort4 o;
    o.x = f2b(v.x); o.y = f2b(v.y); o.z = f2b(v.z); o.w = f2b(v.w);
    *(ushort4*)&outp[(size_t)i * 4] = o;
}

// ---------------- Wqk precompute ----------------
template <int D, int OUT>
__global__ __launch_bounds__(256) void k_wqk(const float* __restrict__ w, const float* __restrict__ q,
                                             const float* __restrict__ k, ushort_t* __restrict__ wqkt) {
    int tid = blockIdx.x * blockDim.x + threadIdx.x;
    if (tid >= 48 * D) return;
    int c = tid / D, i = tid % D;
    int r = c / 6, j = c % 6;
    const float* qk = (j < 3) ? q : k;
    int jj = (j < 3) ? j : j - 3;
    const float* wrow = w + ((size_t)r * D + i) * OUT;
    float s = 0.f;
    for (int o = 0; o < OUT; o++) s += wrow[o] * qk[o * 3 + jj];
    wqkt[(size_t)c * D + i] = f2b(s);
}

// ---------------- Wagg precompute: Bt[o][(r*3+h)*D + i] = w[r][i][h*OC + o] ----------------
template <int D, int OC>
__global__ __launch_bounds__(256) void k_wagg(const float* __restrict__ w, ushort_t* __restrict__ outp) {
    const int KT = RELS * 3 * D;
    int tid = blockIdx.x * blockDim.x + threadIdx.x;
    if (tid >= OC * KT) return;
    int o = tid / KT, kidx = tid % KT;
    int r = kidx / (3 * D), h = (kidx / D) % 3, i = kidx % D;
    float v = w[((size_t)r * D + i) * (3 * OC) + h * OC + o];
    outp[tid] = f2b(v);
}

// ---------------- CSR build over keys = dst*8 + rel ----------------
__global__ __launch_bounds__(256) void k_count(const int* __restrict__ dst, const int* __restrict__ et,
                                               int* __restrict__ counts) {
    int e = blockIdx.x * blockDim.x + threadIdx.x;
    if (e < N_EDGES) atomicAdd(&counts[dst[e] * 8 + et[e]], 1);
}

// ---------------- hierarchical scan ----------------
__global__ __launch_bounds__(256) void k_scanA(const int* __restrict__ counts, int* __restrict__ keyoff,
                                               int* __restrict__ blocksum) {
    __shared__ int part[256];
    int b = blockIdx.x, tid = threadIdx.x;
    int base = b * SCAN_CHUNK + tid * 4;
    int4 c = make_int4(0, 0, 0, 0);
    if (base + 3 < NKEYS) c = *(const int4*)&counts[base];
    else {
        if (base + 0 < NKEYS) c.x = counts[base + 0];
        if (base + 1 < NKEYS) c.y = counts[base + 1];
        if (base + 2 < NKEYS) c.z = counts[base + 2];
        if (base + 3 < NKEYS) c.w = counts[base + 3];
    }
    int s = c.x + c.y + c.z + c.w;
    part[tid] = s;
    __syncthreads();
    for (int off = 1; off < 256; off <<= 1) {
        int v = (tid >= off) ? part[tid - off] : 0;
        __syncthreads();
        part[tid] += v;
        __syncthreads();
    }
    int excl = part[tid] - s;
    int4 o;
    o.x = excl;
    o.y = excl + c.x;
    o.z = excl + c.x + c.y;
    o.w = excl + c.x + c.y + c.z;
    if (base + 3 < NKEYS) *(int4*)&keyoff[base] = o;
    else {
        if (base + 0 < NKEYS) keyoff[base + 0] = o.x;
        if (base + 1 < NKEYS) keyoff[base + 1] = o.y;
        if (base + 2 < NKEYS) keyoff[base + 2] = o.z;
        if (base + 3 < NKEYS) keyoff[base + 3] = o.w;
    }
    if (tid == 255) blocksum[b] = part[255];
}

__global__ __launch_bounds__(256) void k_scanB(int* __restrict__ blocksum, int* __restrict__ blockbase,
                                               int* __restrict__ keyoff) {
    __shared__ int part[256];
    int tid = threadIdx.x;
    int v0 = (tid < SCAN_NBLK) ? blocksum[tid] : 0;
    part[tid] = v0;
    __syncthreads();
    for (int off = 1; off < 256; off <<= 1) {
        int v = (tid >= off) ? part[tid - off] : 0;
        __syncthreads();
        part[tid] += v;
        __syncthreads();
    }
    if (tid < SCAN_NBLK) blockbase[tid] = part[tid] - v0;
    if (tid == 255) keyoff[NKEYS] = part[255];
}

__global__ __launch_bounds__(256) void k_scanC(const int* __restrict__ blockbase, int* __restrict__ keyoff,
                                               int* __restrict__ cursor) {
    int b = blockIdx.x, tid = threadIdx.x;
    int base = b * SCAN_CHUNK + tid * 4;
    int add = blockbase[b];
    if (base + 3 < NKEYS) {
        int4 v = *(const int4*)&keyoff[base];
        v.x += add; v.y += add; v.z += add; v.w += add;
        *(int4*)&keyoff[base] = v;
        *(int4*)&cursor[base] = v;
    } else {
        for (int j = 0; j < 4; j++) {
            if (base + j < NKEYS) {
                int v = keyoff[base + j] + add;
                keyoff[base + j] = v;
                cursor[base + j] = v;
            }
        }
    }
}

// ---------------- direct-fragment MFMA GEMM (used for qkd projections) ----------------
template <int K, int KCH, int N, int MREP, int NREP>
__global__ __launch_bounds__(256) void k_mfma_gemm(const ushort_t* __restrict__ A, const ushort_t* __restrict__ Bt,
                                                   float* __restrict__ outp, int M) {
    const int wid = threadIdx.x >> 6;
    const int lane = threadIdx.x & 63;
    const int m0 = blockIdx.x * (4 * MREP * 16) + wid * (MREP * 16);
    const int kbase = blockIdx.y * KCH;
    const int l15 = lane & 15;
    const int kq = (lane >> 4) * 8;

    f32x4 acc[MREP][NREP] = {};
    for (int kk = kbase; kk < kbase + KCH; kk += 32) {
        bf16x8 a[MREP], b[NREP];
#pragma unroll
        for (int i = 0; i < MREP; i++) {
            int row = m0 + i * 16 + l15;
            row = row < M ? row : M - 1;
            a[i] = *(const bf16x8*)&A[(size_t)row * K + kk + kq];
        }
#pragma unroll
        for (int j = 0; j < NREP; j++) b[j] = *(const bf16x8*)&Bt[(size_t)(j * 16 + l15) * K + kk + kq];
#pragma unroll
        for (int i = 0; i < MREP; i++)
#pragma unroll
            for (int j = 0; j < NREP; j++)
                acc[i][j] = __builtin_amdgcn_mfma_f32_16x16x32_bf16(a[i], b[j], acc[i][j], 0, 0, 0);
    }
    float* op = outp + (size_t)blockIdx.y * M * N;
    const int r4 = (lane >> 4) * 4;
#pragma unroll
    for (int i = 0; i < MREP; i++) {
#pragma unroll
        for (int j = 0; j < NREP; j++) {
#pragma unroll
            for (int g = 0; g < 4; g++) {
                int row = m0 + i * 16 + r4 + g;
                if (row < M) op[(size_t)row * N + j * 16 + l15] = acc[i][j][g];
            }
        }
    }
}

// ---------------- scatter + fused attention logits (layer 1) ----------------
__global__ __launch_bounds__(256) void k_scatter_alpha(const int* __restrict__ src, const int* __restrict__ dst,
                                                       const int* __restrict__ et, const float* __restrict__ qkd,
                                                       int* __restrict__ cursor, int* __restrict__ srcs,
                                                       int* __restrict__ inv, float* __restrict__ alpha) {
    int e = blockIdx.x * blockDim.x + threadIdx.x;
    if (e >= N_EDGES) return;
    int d = dst[e], s = src[e], r = et[e];
    int p = atomicAdd(&cursor[d * 8 + r], 1);
    srcs[p] = s;
    inv[e] = p;
    const float* qrow = qkd + (size_t)d * 48 + r * 6;
    const float* krow = qkd + (size_t)s * 48 + r * 6 + 3;
#pragma unroll
    for (int h = 0; h < 3; h++) {
        float a = qrow[h] + krow[h];
        alpha[(size_t)p * 3 + h] = (a > 0.f) ? a : NEG * a;
    }
}

// ---------------- attention logits layer 2 (reuses slot mapping) ----------------
__global__ __launch_bounds__(256) void k_alpha2(const int* __restrict__ src, const int* __restrict__ dst,
                                                const int* __restrict__ et, const int* __restrict__ inv,
                                                const float* __restrict__ qkd, float* __restrict__ alpha) {
    int e = blockIdx.x * blockDim.x + threadIdx.x;
    if (e >= N_EDGES) return;
    int d = dst[e], s = src[e], r = et[e];
    int p = inv[e];
    const float* qrow = qkd + (size_t)d * 48 + r * 6;
    const float* krow = qkd + (size_t)s * 48 + r * 6 + 3;
#pragma unroll
    for (int h = 0; h < 3; h++) {
        float a = qrow[h] + krow[h];
        alpha[(size_t)p * 3 + h] = (a > 0.f) ? a : NEG * a;
    }
}

// ---------------- per-node softmax -> normalized weights (CSR-contiguous alpha) ----------------
__global__ __launch_bounds__(256) void k_stats(const int* __restrict__ keyoff, const float* __restrict__ alpha,
                                               float* __restrict__ wcsr) {
    int node = blockIdx.x * 4 + (threadIdx.x >> 6);
    int lane = threadIdx.x & 63;
    int beg = keyoff[node * 8], end = keyoff[node * 8 + 8];
    int deg = end - beg;
    if (deg == 0) return;

    if (deg <= 64) {
        float a0 = -INFINITY, a1 = -INFINITY, a2 = -INFINITY;
        if (lane < deg) {
            size_t p = (size_t)(beg + lane) * 3;
            a0 = alpha[p + 0];
            a1 = alpha[p + 1];
            a2 = alpha[p + 2];
        }
        float m0 = a0, m1 = a1, m2 = a2;
#pragma unroll
        for (int off = 32; off >= 1; off >>= 1) {
            m0 = fmaxf(m0, __shfl_xor(m0, off));
            m1 = fmaxf(m1, __shfl_xor(m1, off));
            m2 = fmaxf(m2, __shfl_xor(m2, off));
        }
        float e0 = 0.f, e1 = 0.f, e2 = 0.f;
        if (lane < deg) {
            e0 = expf(a0 - m0);
            e1 = expf(a1 - m1);
            e2 = expf(a2 - m2);
        }
        float s0 = e0, s1 = e1, s2 = e2;
#pragma unroll
        for (int off = 32; off >= 1; off >>= 1) {
            s0 += __shfl_xor(s0, off);
            s1 += __shfl_xor(s1, off);
            s2 += __shfl_xor(s2, off);
        }
        float i0 = 1.f / (3.f * (s0 + 1e-16f));
        float i1 = 1.f / (3.f * (s1 + 1e-16f));
        float i2 = 1.f / (3.f * (s2 + 1e-16f));
        if (lane < deg) {
            size_t p = (size_t)(beg + lane) * 3;
            wcsr[p + 0] = e0 * i0;
            wcsr[p + 1] = e1 * i1;
            wcsr[p + 2] = e2 * i2;
        }
    } else {
        float m0 = -INFINITY, m1 = -INFINITY, m2 = -INFINITY;
        for (int i = beg + lane; i < end; i += 64) {
            size_t p = (size_t)i * 3;
            m0 = fmaxf(m0, alpha[p + 0]);
            m1 = fmaxf(m1, alpha[p + 1]);
            m2 = fmaxf(m2, alpha[p + 2]);
        }
#pragma unroll
        for (int off = 32; off >= 1; off >>= 1) {
            m0 = fmaxf(m0, __shfl_xor(m0, off));
            m1 = fmaxf(m1, __shfl_xor(m1, off));
            m2 = fmaxf(m2, __shfl_xor(m2, off));
        }
        float s0 = 0.f, s1 = 0.f, s2 = 0.f;
        for (int i = beg + lane; i < end; i += 64) {
            size_t p = (size_t)i * 3;
            s0 += expf(alpha[p + 0] - m0);
            s1 += expf(alpha[p + 1] - m1);
            s2 += expf(alpha[p + 2] - m2);
        }
#pragma unroll
        for (int off = 32; off >= 1; off >>= 1) {
            s0 += __shfl_xor(s0, off);
            s1 += __shfl_xor(s1, off);
            s2 += __shfl_xor(s2, off);
        }
        float i0 = 1.f / (3.f * (s0 + 1e-16f));
        float i1 = 1.f / (3.f * (s1 + 1e-16f));
        float i2 = 1.f / (3.f * (s2 + 1e-16f));
        for (int i = beg + lane; i < end; i += 64) {
            size_t p = (size_t)i * 3;
            wcsr[p + 0] = expf(alpha[p + 0] - m0) * i0;
            wcsr[p + 1] = expf(alpha[p + 1] - m1) * i1;
            wcsr[p + 2] = expf(alpha[p + 2] - m2) * i2;
        }
    }
}

// ---------------- FUSED layer 1: gather-aggregate (LDS) + MFMA transform + bias/relu ----------------
// Per block: 64 dst nodes, 4 waves, wave-private (no barriers). Wave owns 16 dst rows.
// For each relation: accumulate T_r[16][384] into LDS, then acc += T_r @ Wagg_r (K=384).
#define PADK1 392  // 384 + 8 -> row stride 784B = 196 dwords, 196%32=4 -> 2-way conflicts (free)
__global__ __launch_bounds__(256) void k_fused1(const int* __restrict__ keyoff, const int* __restrict__ srcs,
                                                const float* __restrict__ wcsr, const ushort_t* __restrict__ x,
                                                const ushort_t* __restrict__ wagg, const float* __restrict__ bias,
                                                ushort_t* __restrict__ x2) {
    __shared__ ushort_t lt[4][16][PADK1];
    const int w = threadIdx.x >> 6, lane = threadIdx.x & 63;
    const int l15 = lane & 15, kq = (lane >> 4) * 8;
    const int nbase = blockIdx.x * 64 + w * 16;

    f32x4 acc[4] = {};
    for (int r = 0; r < 8; r++) {
        // --- accumulate phase: one node at a time, full wave = 128 cols (2/lane) ---
        for (int n = 0; n < 16; n++) {
            int dst = nbase + n;
            int key = (dst < N_NODES) ? dst * 8 + r : 0;
            int beg = (dst < N_NODES) ? keyoff[key] : 0;
            int end = (dst < N_NODES) ? keyoff[key + 1] : 0;
            float a0 = 0.f, a1 = 0.f, a2 = 0.f, c0 = 0.f, c1 = 0.f, c2 = 0.f;
            for (int s = beg; s < end; s++) {
                int sv = srcs[s];
                float w0 = wcsr[(size_t)s * 3 + 0];
                float w1 = wcsr[(size_t)s * 3 + 1];
                float w2 = wcsr[(size_t)s * 3 + 2];
                ushort2 xv = *(const ushort2*)&x[(size_t)sv * 128 + lane * 2];
                float f0 = b2f(xv.x), f1 = b2f(xv.y);
                a0 += w0 * f0; c0 += w0 * f1;
                a1 += w1 * f0; c1 += w1 * f1;
                a2 += w2 * f0; c2 += w2 * f1;
            }
            *(ushort2*)&lt[w][n][0 * 128 + lane * 2] = make_ushort2(f2b(a0), f2b(c0));
            *(ushort2*)&lt[w][n][1 * 128 + lane * 2] = make_ushort2(f2b(a1), f2b(c1));
            *(ushort2*)&lt[w][n][2 * 128 + lane * 2] = make_ushort2(f2b(a2), f2b(c2));
        }
        // --- MFMA phase: K=384 (12 k-steps), N=64 (NREP=4) ---
#pragma unroll
        for (int ks = 0; ks < 12; ks++) {
            int kk = ks * 32;
            bf16x8 a = *(const bf16x8*)&lt[w][l15][kk + kq];
#pragma unroll
            for (int j = 0; j < 4; j++) {
                bf16x8 b = *(const bf16x8*)&wagg[(size_t)(j * 16 + l15) * 3072 + r * 384 + kk + kq];
                acc[j] = __builtin_amdgcn_mfma_f32_16x16x32_bf16(a, b, acc[j], 0, 0, 0);
            }
        }
    }
    const int r4 = (lane >> 4) * 4;
#pragma unroll
    for (int j = 0; j < 4; j++) {
#pragma unroll
        for (int g = 0; g < 4; g++) {
            int row = nbase + r4 + g;
            if (row < N_NODES) {
                float v = acc[j][g] + bias[j * 16 + l15];
                x2[(size_t)row * 64 + j * 16 + l15] = f2b(v > 0.f ? v : 0.f);
            }
        }
    }
}

// ---------------- FUSED layer 2: gather-aggregate + MFMA + bias/sigmoid ----------------
#define PADK2 200  // 192 + 8 -> 400B = 100 dwords, 100%32=4 -> 2-way (free)
__global__ __launch_bounds__(256) void k_fused2(const int* __restrict__ keyoff, const int* __restrict__ srcs,
                                                const float* __restrict__ wcsr, const ushort_t* __restrict__ x2,
                                                const ushort_t* __restrict__ wagg, const float* __restrict__ bias,
                                                float* __restrict__ outp) {
    __shared__ ushort_t lt[4][16][PADK2];
    const int w = threadIdx.x >> 6, lane = threadIdx.x & 63;
    const int l15 = lane & 15, kq = (lane >> 4) * 8;
    const int nbase = blockIdx.x * 64 + w * 16;

    f32x4 acc = {};
    for (int r = 0; r < 8; r++) {
        for (int n = 0; n < 16; n++) {
            int dst = nbase + n;
            int key = (dst < N_NODES) ? dst * 8 + r : 0;
            int beg = (dst < N_NODES) ? keyoff[key] : 0;
            int end = (dst < N_NODES) ? keyoff[key + 1] : 0;
            float a0 = 0.f, a1 = 0.f, a2 = 0.f;
            for (int s = beg; s < end; s++) {
                int sv = srcs[s];
                float w0 = wcsr[(size_t)s * 3 + 0];
                float w1 = wcsr[(size_t)s * 3 + 1];
                float w2 = wcsr[(size_t)s * 3 + 2];
                float f0 = b2f(x2[(size_t)sv * 64 + lane]);
                a0 += w0 * f0;
                a1 += w1 * f0;
                a2 += w2 * f0;
            }
            lt[w][n][0 * 64 + lane] = f2b(a0);
            lt[w][n][1 * 64 + lane] = f2b(a1);
            lt[w][n][2 * 64 + lane] = f2b(a2);
        }
#pragma unroll
        for (int ks = 0; ks < 6; ks++) {
            int kk = ks * 32;
            bf16x8 a = *(const bf16x8*)&lt[w][l15][kk + kq];
            bf16x8 b = *(const bf16x8*)&wagg[(size_t)l15 * 1536 + r * 192 + kk + kq];
            acc = __builtin_amdgcn_mfma_f32_16x16x32_bf16(a, b, acc, 0, 0, 0);
        }
    }
    const int r4 = (lane >> 4) * 4;
#pragma unroll
    for (int g = 0; g < 4; g++) {
        int row = nbase + r4 + g;
        if (row < N_NODES) {
            float v = acc[g] + bias[l15];
            outp[(size_t)row * 16 + l15] = 1.f / (1.f + expf(-v));
        }
    }
}

extern "C" void kernel_launch(void* const* d_in, const int* in_sizes, int n_in, void* d_out, int out_size,
                              void* d_ws, size_t ws_size, hipStream_t stream) {
    const float* emb = (const float*)d_in[0];
    const float* w1 = (const float*)d_in[1];
    const float* q1 = (const float*)d_in[2];
    const float* k1 = (const float*)d_in[3];
    const float* b1 = (const float*)d_in[4];
    const float* w2 = (const float*)d_in[5];
    const float* q2 = (const float*)d_in[6];
    const float* k2 = (const float*)d_in[7];
    const float* b2 = (const float*)d_in[8];
    const int* eidx = (const int*)d_in[9];
    const int* etype = (const int*)d_in[10];
    const int* srcv = eidx;
    const int* dstv = eidx + N_EDGES;
    float* out = (float*)d_out;

    char* p = (char*)d_ws;
    auto alloc = [&](size_t bytes) -> void* {
        void* q = p;
        p += (bytes + 255) & ~(size_t)255;
        return q;
    };
    int* counts = (int*)alloc((size_t)NKEYS * 4);
    int* keyoff = (int*)alloc((size_t)(NKEYS + 1) * 4);
    int* cursor = (int*)alloc((size_t)NKEYS * 4);
    int* blocksum = (int*)alloc((size_t)SCAN_NBLK * 4);
    int* blockbase = (int*)alloc((size_t)SCAN_NBLK * 4);
    int* srcs = (int*)alloc((size_t)N_EDGES * 4);
    int* inv = (int*)alloc((size_t)N_EDGES * 4);
    ushort_t* emb_b = (ushort_t*)alloc((size_t)N_NODES * EMB * 2);
    ushort_t* wqkt1 = (ushort_t*)alloc((size_t)48 * 128 * 2);
    ushort_t* wagg1 = (ushort_t*)alloc((size_t)64 * 3072 * 2);
    ushort_t* wqkt2 = (ushort_t*)alloc((size_t)48 * 64 * 2);
    ushort_t* wagg2 = (ushort_t*)alloc((size_t)16 * 1536 * 2);
    float* qkd = (float*)alloc((size_t)N_NODES * 48 * 4);
    float* alpha = (float*)alloc((size_t)N_EDGES * 3 * 4);
    float* wcsr = (float*)alloc((size_t)N_EDGES * 3 * 4);
    ushort_t* x2 = (ushort_t*)alloc((size_t)N_NODES * 64 * 2);

    // ---- precomputes ----
    k_cvt<<<(N_NODES * EMB / 4 + 255) / 256, 256, 0, stream>>>(emb, emb_b, N_NODES * EMB / 4);
    k_wqk<128, 192><<<(48 * 128 + 255) / 256, 256, 0, stream>>>(w1, q1, k1, wqkt1);
    k_wqk<64, 48><<<(48 * 64 + 255) / 256, 256, 0, stream>>>(w2, q2, k2, wqkt2);
    k_wagg<128, 64><<<(64 * 3072 + 255) / 256, 256, 0, stream>>>(w1, wagg1);
    k_wagg<64, 16><<<(16 * 1536 + 255) / 256, 256, 0, stream>>>(w2, wagg2);

    // ---- CSR over (dst, rel) ----
    hipMemsetAsync(counts, 0, (size_t)NKEYS * 4, stream);
    k_count<<<(N_EDGES + 255) / 256, 256, 0, stream>>>(dstv, etype, counts);
    k_scanA<<<SCAN_NBLK, 256, 0, stream>>>(counts, keyoff, blocksum);
    k_scanB<<<1, 256, 0, stream>>>(blocksum, blockbase, keyoff);
    k_scanC<<<SCAN_NBLK, 256, 0, stream>>>(blockbase, keyoff, cursor);

    // ---- layer 1 ----
    k_mfma_gemm<128, 128, 48, 1, 3><<<dim3(313, 1), 256, 0, stream>>>(emb_b, wqkt1, qkd, N_NODES);
    k_scatter_alpha<<<(N_EDGES + 255) / 256, 256, 0, stream>>>(srcv, dstv, etype, qkd, cursor, srcs, inv, alpha);
    k_stats<<<N_NODES / 4, 256, 0, stream>>>(keyoff, alpha, wcsr);
    k_fused1<<<(N_NODES + 63) / 64, 256, 0, stream>>>(keyoff, srcs, wcsr, emb_b, wagg1, b1, x2);

    // ---- layer 2 ----
    k_mfma_gemm<64, 64, 48, 1, 3><<<dim3(313, 1), 256, 0, stream>>>(x2, wqkt2, qkd, N_NODES);
    k_alpha2<<<(N_EDGES + 255) / 256, 256, 0, stream>>>(srcv, dstv, etype, inv, qkd, alpha);
    k_stats<<<N_NODES / 4, 256, 0, stream>>>(keyoff, alpha, wcsr);
    k_fused2<<<(N_NODES + 63) / 64, 256, 0, stream>>>(keyoff, srcs, wcsr, x2, wagg2, b2, out);
}

// Round 6
// 356.695 us; speedup vs baseline: 1.9866x; 1.9866x over previous
//
#include <hip/hip_runtime.h>
#include <hip/hip_bf16.h>
#include <math.h>

#define N_NODES 20000
#define EMB 128
#define HID 64
#define RELS 8
#define CLS 16
#define N_EDGES 640000
#define NEG 0.2f
#define NKEYS (N_NODES * RELS)
#define SCAN_CHUNK 1024
#define SCAN_NBLK ((NKEYS + SCAN_CHUNK - 1) / SCAN_CHUNK)  // 157
#define CAP_E 768  // cached edges per 16-node block (avg 512, +11 sigma)

typedef unsigned short ushort_t;
typedef __attribute__((ext_vector_type(8))) short bf16x8;
typedef __attribute__((ext_vector_type(4))) float f32x4;

__device__ __forceinline__ float b2f(ushort_t u) {
    return __uint_as_float(((unsigned int)u) << 16);
}
__device__ __forceinline__ ushort_t f2b(float f) {
    __hip_bfloat16 h = __float2bfloat16(f);
    return *reinterpret_cast<ushort_t*>(&h);
}

// ---------------- f32 -> bf16 conversion (vectorized) ----------------
__global__ __launch_bounds__(256) void k_cvt(const float* __restrict__ in, ushort_t* __restrict__ outp, int n4) {
    int i = blockIdx.x * blockDim.x + threadIdx.x;
    if (i >= n4) return;
    float4 v = *(const float4*)&in[(size_t)i * 4];
    ushort4 o;
    o.x = f2b(v.x); o.y = f2b(v.y); o.z = f2b(v.z); o.w = f2b(v.w);
    *(ushort4*)&outp[(size_t)i * 4] = o;
}

// ---------------- Wqk precompute ----------------
template <int D, int OUT>
__global__ __launch_bounds__(256) void k_wqk(const float* __restrict__ w, const float* __restrict__ q,
                                             const float* __restrict__ k, ushort_t* __restrict__ wqkt) {
    int tid = blockIdx.x * blockDim.x + threadIdx.x;
    if (tid >= 48 * D) return;
    int c = tid / D, i = tid % D;
    int r = c / 6, j = c % 6;
    const float* qk = (j < 3) ? q : k;
    int jj = (j < 3) ? j : j - 3;
    const float* wrow = w + ((size_t)r * D + i) * OUT;
    float s = 0.f;
    for (int o = 0; o < OUT; o++) s += wrow[o] * qk[o * 3 + jj];
    wqkt[(size_t)c * D + i] = f2b(s);
}

// ---------------- Wagg precompute: Bt[o][(r*3+h)*D + i] = w[r][i][h*OC + o] ----------------
template <int D, int OC>
__global__ __launch_bounds__(256) void k_wagg(const float* __restrict__ w, ushort_t* __restrict__ outp) {
    const int KT = RELS * 3 * D;
    int tid = blockIdx.x * blockDim.x + threadIdx.x;
    if (tid >= OC * KT) return;
    int o = tid / KT, kidx = tid % KT;
    int r = kidx / (3 * D), h = (kidx / D) % 3, i = kidx % D;
    float v = w[((size_t)r * D + i) * (3 * OC) + h * OC + o];
    outp[tid] = f2b(v);
}

// ---------------- CSR build over keys = dst*8 + rel ----------------
__global__ __launch_bounds__(256) void k_count(const int* __restrict__ dst, const int* __restrict__ et,
                                               int* __restrict__ counts) {
    int e = blockIdx.x * blockDim.x + threadIdx.x;
    if (e < N_EDGES) atomicAdd(&counts[dst[e] * 8 + et[e]], 1);
}

// ---------------- hierarchical scan ----------------
__global__ __launch_bounds__(256) void k_scanA(const int* __restrict__ counts, int* __restrict__ keyoff,
                                               int* __restrict__ blocksum) {
    __shared__ int part[256];
    int b = blockIdx.x, tid = threadIdx.x;
    int base = b * SCAN_CHUNK + tid * 4;
    int4 c = make_int4(0, 0, 0, 0);
    if (base + 3 < NKEYS) c = *(const int4*)&counts[base];
    else {
        if (base + 0 < NKEYS) c.x = counts[base + 0];
        if (base + 1 < NKEYS) c.y = counts[base + 1];
        if (base + 2 < NKEYS) c.z = counts[base + 2];
        if (base + 3 < NKEYS) c.w = counts[base + 3];
    }
    int s = c.x + c.y + c.z + c.w;
    part[tid] = s;
    __syncthreads();
    for (int off = 1; off < 256; off <<= 1) {
        int v = (tid >= off) ? part[tid - off] : 0;
        __syncthreads();
        part[tid] += v;
        __syncthreads();
    }
    int excl = part[tid] - s;
    int4 o;
    o.x = excl;
    o.y = excl + c.x;
    o.z = excl + c.x + c.y;
    o.w = excl + c.x + c.y + c.z;
    if (base + 3 < NKEYS) *(int4*)&keyoff[base] = o;
    else {
        if (base + 0 < NKEYS) keyoff[base + 0] = o.x;
        if (base + 1 < NKEYS) keyoff[base + 1] = o.y;
        if (base + 2 < NKEYS) keyoff[base + 2] = o.z;
        if (base + 3 < NKEYS) keyoff[base + 3] = o.w;
    }
    if (tid == 255) blocksum[b] = part[255];
}

__global__ __launch_bounds__(256) void k_scanB(int* __restrict__ blocksum, int* __restrict__ blockbase,
                                               int* __restrict__ keyoff) {
    __shared__ int part[256];
    int tid = threadIdx.x;
    int v0 = (tid < SCAN_NBLK) ? blocksum[tid] : 0;
    part[tid] = v0;
    __syncthreads();
    for (int off = 1; off < 256; off <<= 1) {
        int v = (tid >= off) ? part[tid - off] : 0;
        __syncthreads();
        part[tid] += v;
        __syncthreads();
    }
    if (tid < SCAN_NBLK) blockbase[tid] = part[tid] - v0;
    if (tid == 255) keyoff[NKEYS] = part[255];
}

__global__ __launch_bounds__(256) void k_scanC(const int* __restrict__ blockbase, int* __restrict__ keyoff,
                                               int* __restrict__ cursor) {
    int b = blockIdx.x, tid = threadIdx.x;
    int base = b * SCAN_CHUNK + tid * 4;
    int add = blockbase[b];
    if (base + 3 < NKEYS) {
        int4 v = *(const int4*)&keyoff[base];
        v.x += add; v.y += add; v.z += add; v.w += add;
        *(int4*)&keyoff[base] = v;
        *(int4*)&cursor[base] = v;
    } else {
        for (int j = 0; j < 4; j++) {
            if (base + j < NKEYS) {
                int v = keyoff[base + j] + add;
                keyoff[base + j] = v;
                cursor[base + j] = v;
            }
        }
    }
}

// ---------------- direct-fragment MFMA GEMM (qkd projections) ----------------
template <int K, int KCH, int N, int MREP, int NREP>
__global__ __launch_bounds__(256) void k_mfma_gemm(const ushort_t* __restrict__ A, const ushort_t* __restrict__ Bt,
                                                   float* __restrict__ outp, int M) {
    const int wid = threadIdx.x >> 6;
    const int lane = threadIdx.x & 63;
    const int m0 = blockIdx.x * (4 * MREP * 16) + wid * (MREP * 16);
    const int kbase = blockIdx.y * KCH;
    const int l15 = lane & 15;
    const int kq = (lane >> 4) * 8;

    f32x4 acc[MREP][NREP] = {};
    for (int kk = kbase; kk < kbase + KCH; kk += 32) {
        bf16x8 a[MREP], b[NREP];
#pragma unroll
        for (int i = 0; i < MREP; i++) {
            int row = m0 + i * 16 + l15;
            row = row < M ? row : M - 1;
            a[i] = *(const bf16x8*)&A[(size_t)row * K + kk + kq];
        }
#pragma unroll
        for (int j = 0; j < NREP; j++) b[j] = *(const bf16x8*)&Bt[(size_t)(j * 16 + l15) * K + kk + kq];
#pragma unroll
        for (int i = 0; i < MREP; i++)
#pragma unroll
            for (int j = 0; j < NREP; j++)
                acc[i][j] = __builtin_amdgcn_mfma_f32_16x16x32_bf16(a[i], b[j], acc[i][j], 0, 0, 0);
    }
    float* op = outp + (size_t)blockIdx.y * M * N;
    const int r4 = (lane >> 4) * 4;
#pragma unroll
    for (int i = 0; i < MREP; i++) {
#pragma unroll
        for (int j = 0; j < NREP; j++) {
#pragma unroll
            for (int g = 0; g < 4; g++) {
                int row = m0 + i * 16 + r4 + g;
                if (row < M) op[(size_t)row * N + j * 16 + l15] = acc[i][j][g];
            }
        }
    }
}

// ---------------- scatter + fused attention logits (layer 1) ----------------
__global__ __launch_bounds__(256) void k_scatter_alpha(const int* __restrict__ src, const int* __restrict__ dst,
                                                       const int* __restrict__ et, const float* __restrict__ qkd,
                                                       int* __restrict__ cursor, int* __restrict__ srcs,
                                                       int* __restrict__ inv, float* __restrict__ alpha) {
    int e = blockIdx.x * blockDim.x + threadIdx.x;
    if (e >= N_EDGES) return;
    int d = dst[e], s = src[e], r = et[e];
    int p = atomicAdd(&cursor[d * 8 + r], 1);
    srcs[p] = s;
    inv[e] = p;
    const float* qrow = qkd + (size_t)d * 48 + r * 6;
    const float* krow = qkd + (size_t)s * 48 + r * 6 + 3;
#pragma unroll
    for (int h = 0; h < 3; h++) {
        float a = qrow[h] + krow[h];
        alpha[(size_t)p * 3 + h] = (a > 0.f) ? a : NEG * a;
    }
}

// ---------------- attention logits layer 2 (reuses slot mapping) ----------------
__global__ __launch_bounds__(256) void k_alpha2(const int* __restrict__ src, const int* __restrict__ dst,
                                                const int* __restrict__ et, const int* __restrict__ inv,
                                                const float* __restrict__ qkd, float* __restrict__ alpha) {
    int e = blockIdx.x * blockDim.x + threadIdx.x;
    if (e >= N_EDGES) return;
    int d = dst[e], s = src[e], r = et[e];
    int p = inv[e];
    const float* qrow = qkd + (size_t)d * 48 + r * 6;
    const float* krow = qkd + (size_t)s * 48 + r * 6 + 3;
#pragma unroll
    for (int h = 0; h < 3; h++) {
        float a = qrow[h] + krow[h];
        alpha[(size_t)p * 3 + h] = (a > 0.f) ? a : NEG * a;
    }
}

// ---------------- per-node softmax -> normalized weights (CSR-contiguous alpha) ----------------
__global__ __launch_bounds__(256) void k_stats(const int* __restrict__ keyoff, const float* __restrict__ alpha,
                                               float* __restrict__ wcsr) {
    int node = blockIdx.x * 4 + (threadIdx.x >> 6);
    int lane = threadIdx.x & 63;
    int beg = keyoff[node * 8], end = keyoff[node * 8 + 8];
    int deg = end - beg;
    if (deg == 0) return;

    if (deg <= 64) {
        float a0 = -INFINITY, a1 = -INFINITY, a2 = -INFINITY;
        if (lane < deg) {
            size_t p = (size_t)(beg + lane) * 3;
            a0 = alpha[p + 0];
            a1 = alpha[p + 1];
            a2 = alpha[p + 2];
        }
        float m0 = a0, m1 = a1, m2 = a2;
#pragma unroll
        for (int off = 32; off >= 1; off >>= 1) {
            m0 = fmaxf(m0, __shfl_xor(m0, off));
            m1 = fmaxf(m1, __shfl_xor(m1, off));
            m2 = fmaxf(m2, __shfl_xor(m2, off));
        }
        float e0 = 0.f, e1 = 0.f, e2 = 0.f;
        if (lane < deg) {
            e0 = expf(a0 - m0);
            e1 = expf(a1 - m1);
            e2 = expf(a2 - m2);
        }
        float s0 = e0, s1 = e1, s2 = e2;
#pragma unroll
        for (int off = 32; off >= 1; off >>= 1) {
            s0 += __shfl_xor(s0, off);
            s1 += __shfl_xor(s1, off);
            s2 += __shfl_xor(s2, off);
        }
        float i0 = 1.f / (3.f * (s0 + 1e-16f));
        float i1 = 1.f / (3.f * (s1 + 1e-16f));
        float i2 = 1.f / (3.f * (s2 + 1e-16f));
        if (lane < deg) {
            size_t p = (size_t)(beg + lane) * 3;
            wcsr[p + 0] = e0 * i0;
            wcsr[p + 1] = e1 * i1;
            wcsr[p + 2] = e2 * i2;
        }
    } else {
        float m0 = -INFINITY, m1 = -INFINITY, m2 = -INFINITY;
        for (int i = beg + lane; i < end; i += 64) {
            size_t p = (size_t)i * 3;
            m0 = fmaxf(m0, alpha[p + 0]);
            m1 = fmaxf(m1, alpha[p + 1]);
            m2 = fmaxf(m2, alpha[p + 2]);
        }
#pragma unroll
        for (int off = 32; off >= 1; off >>= 1) {
            m0 = fmaxf(m0, __shfl_xor(m0, off));
            m1 = fmaxf(m1, __shfl_xor(m1, off));
            m2 = fmaxf(m2, __shfl_xor(m2, off));
        }
        float s0 = 0.f, s1 = 0.f, s2 = 0.f;
        for (int i = beg + lane; i < end; i += 64) {
            size_t p = (size_t)i * 3;
            s0 += expf(alpha[p + 0] - m0);
            s1 += expf(alpha[p + 1] - m1);
            s2 += expf(alpha[p + 2] - m2);
        }
#pragma unroll
        for (int off = 32; off >= 1; off >>= 1) {
            s0 += __shfl_xor(s0, off);
            s1 += __shfl_xor(s1, off);
            s2 += __shfl_xor(s2, off);
        }
        float i0 = 1.f / (3.f * (s0 + 1e-16f));
        float i1 = 1.f / (3.f * (s1 + 1e-16f));
        float i2 = 1.f / (3.f * (s2 + 1e-16f));
        for (int i = beg + lane; i < end; i += 64) {
            size_t p = (size_t)i * 3;
            wcsr[p + 0] = expf(alpha[p + 0] - m0) * i0;
            wcsr[p + 1] = expf(alpha[p + 1] - m1) * i1;
            wcsr[p + 2] = expf(alpha[p + 2] - m2) * i2;
        }
    }
}

// ---------------- FUSED layer 1 v2: 16 nodes/block, 4 waves ----------------
// Per rel: waves gather 4 nodes each into shared T[16][384] (half-wave split),
// barrier, each wave MFMAs its own N-quadrant (j=w), barrier.
#define PADK1 392
__global__ __launch_bounds__(256) void k_fused1(const int* __restrict__ keyoff, const int* __restrict__ srcs,
                                                const float* __restrict__ wcsr, const ushort_t* __restrict__ x,
                                                const ushort_t* __restrict__ wagg, const float* __restrict__ bias,
                                                ushort_t* __restrict__ x2) {
    __shared__ ushort_t lt[16][PADK1];  // 12.5 KB
    __shared__ int koffs[129];
    __shared__ int esrc[CAP_E];  // 3 KB
    const int tid = threadIdx.x;
    const int w = tid >> 6, lane = tid & 63;
    const int hv = lane >> 5, hl = lane & 31;
    const int l15 = lane & 15, kq = (lane >> 4) * 8;
    const int nbase = blockIdx.x * 16;

    // cooperative prefetch of the block's CSR slice
    const int bbeg = keyoff[nbase * 8];
    const int bdeg = keyoff[nbase * 8 + 128] - bbeg;
    if (tid < 129) koffs[tid] = keyoff[nbase * 8 + tid];
    for (int i = tid; i < bdeg && i < CAP_E; i += 256) esrc[i] = srcs[bbeg + i];
    __syncthreads();

    f32x4 acc = {};
    for (int r = 0; r < 8; r++) {
        // gather phase: wave w -> tile rows w*4..w*4+3
#pragma unroll 1
        for (int n = 0; n < 4; n++) {
            int loc = (w * 4 + n) * 8 + r;
            int beg = koffs[loc], end = koffs[loc + 1];
            float ac[3][4] = {};
            for (int s = beg + hv; s < end; s += 2) {
                int idx = s - bbeg;
                int sv;
                if (idx < CAP_E) sv = esrc[idx];
                else sv = srcs[s];
                float w0 = wcsr[(size_t)s * 3 + 0];
                float w1 = wcsr[(size_t)s * 3 + 1];
                float w2 = wcsr[(size_t)s * 3 + 2];
                ushort4 xv = *(const ushort4*)&x[(size_t)sv * 128 + hl * 4];
                float f[4] = {b2f(xv.x), b2f(xv.y), b2f(xv.z), b2f(xv.w)};
#pragma unroll
                for (int c = 0; c < 4; c++) {
                    ac[0][c] += w0 * f[c];
                    ac[1][c] += w1 * f[c];
                    ac[2][c] += w2 * f[c];
                }
            }
#pragma unroll
            for (int h = 0; h < 3; h++)
#pragma unroll
                for (int c = 0; c < 4; c++) ac[h][c] += __shfl_xor(ac[h][c], 32);
            if (hv == 0) {
                int row = w * 4 + n;
#pragma unroll
                for (int h = 0; h < 3; h++) {
                    *(ushort4*)&lt[row][h * 128 + hl * 4] =
                        make_ushort4(f2b(ac[h][0]), f2b(ac[h][1]), f2b(ac[h][2]), f2b(ac[h][3]));
                }
            }
        }
        __syncthreads();
        // MFMA phase: wave w computes output quadrant cols [w*16, w*16+16)
#pragma unroll
        for (int ks = 0; ks < 12; ks++) {
            bf16x8 a = *(const bf16x8*)&lt[l15][ks * 32 + kq];
            bf16x8 b = *(const bf16x8*)&wagg[(size_t)(w * 16 + l15) * 3072 + r * 384 + ks * 32 + kq];
            acc = __builtin_amdgcn_mfma_f32_16x16x32_bf16(a, b, acc, 0, 0, 0);
        }
        __syncthreads();
    }
    const int r4 = (lane >> 4) * 4;
#pragma unroll
    for (int g = 0; g < 4; g++) {
        int row = nbase + r4 + g;
        float v = acc[g] + bias[w * 16 + l15];
        x2[(size_t)row * 64 + w * 16 + l15] = f2b(v > 0.f ? v : 0.f);
    }
}

// ---------------- FUSED layer 2 v2: 16 nodes/block, wave owns 2 relations ----------------
#define PADK2 200
__global__ __launch_bounds__(256) void k_fused2(const int* __restrict__ keyoff, const int* __restrict__ srcs,
                                                const float* __restrict__ wcsr, const ushort_t* __restrict__ x2in,
                                                const ushort_t* __restrict__ wagg, const float* __restrict__ bias,
                                                float* __restrict__ outp) {
    __shared__ ushort_t lt2[4][16][PADK2];  // 25.6 KB (wave-private tiles)
    __shared__ int koffs[129];
    __shared__ int esrc[CAP_E];
    __shared__ float red[4][16][17];  // padded cross-wave reduce
    const int tid = threadIdx.x;
    const int w = tid >> 6, lane = tid & 63;
    const int hv = lane >> 5, hl = lane & 31;
    const int l15 = lane & 15, kq = (lane >> 4) * 8;
    const int nbase = blockIdx.x * 16;

    const int bbeg = keyoff[nbase * 8];
    const int bdeg = keyoff[nbase * 8 + 128] - bbeg;
    if (tid < 129) koffs[tid] = keyoff[nbase * 8 + tid];
    for (int i = tid; i < bdeg && i < CAP_E; i += 256) esrc[i] = srcs[bbeg + i];
    __syncthreads();

    f32x4 acc = {};
#pragma unroll
    for (int rr = 0; rr < 2; rr++) {
        int r = w * 2 + rr;
#pragma unroll 1
        for (int n = 0; n < 16; n++) {
            int loc = n * 8 + r;
            int beg = koffs[loc], end = koffs[loc + 1];
            float ac[3][2] = {};
            for (int s = beg + hv; s < end; s += 2) {
                int idx = s - bbeg;
                int sv;
                if (idx < CAP_E) sv = esrc[idx];
                else sv = srcs[s];
                float w0 = wcsr[(size_t)s * 3 + 0];
                float w1 = wcsr[(size_t)s * 3 + 1];
                float w2 = wcsr[(size_t)s * 3 + 2];
                ushort2 xv = *(const ushort2*)&x2in[(size_t)sv * 64 + hl * 2];
                float f0 = b2f(xv.x), f1 = b2f(xv.y);
                ac[0][0] += w0 * f0; ac[0][1] += w0 * f1;
                ac[1][0] += w1 * f0; ac[1][1] += w1 * f1;
                ac[2][0] += w2 * f0; ac[2][1] += w2 * f1;
            }
#pragma unroll
            for (int h = 0; h < 3; h++)
#pragma unroll
                for (int c = 0; c < 2; c++) ac[h][c] += __shfl_xor(ac[h][c], 32);
            if (hv == 0) {
#pragma unroll
                for (int h = 0; h < 3; h++)
                    *(ushort2*)&lt2[w][n][h * 64 + hl * 2] = make_ushort2(f2b(ac[h][0]), f2b(ac[h][1]));
            }
        }
        // wave-private MFMA over this relation (K=192)
#pragma unroll
        for (int ks = 0; ks < 6; ks++) {
            bf16x8 a = *(const bf16x8*)&lt2[w][l15][ks * 32 + kq];
            bf16x8 b = *(const bf16x8*)&wagg[(size_t)l15 * 1536 + r * 192 + ks * 32 + kq];
            acc = __builtin_amdgcn_mfma_f32_16x16x32_bf16(a, b, acc, 0, 0, 0);
        }
    }
    const int r4 = (lane >> 4) * 4;
#pragma unroll
    for (int g = 0; g < 4; g++) red[w][r4 + g][l15] = acc[g];
    __syncthreads();
    int row = tid >> 4, col = tid & 15;
    float v = red[0][row][col] + red[1][row][col] + red[2][row][col] + red[3][row][col] + bias[col];
    outp[(size_t)(nbase + row) * 16 + col] = 1.f / (1.f + expf(-v));
}

extern "C" void kernel_launch(void* const* d_in, const int* in_sizes, int n_in, void* d_out, int out_size,
                              void* d_ws, size_t ws_size, hipStream_t stream) {
    const float* emb = (const float*)d_in[0];
    const float* w1 = (const float*)d_in[1];
    const float* q1 = (const float*)d_in[2];
    const float* k1 = (const float*)d_in[3];
    const float* b1 = (const float*)d_in[4];
    const float* w2 = (const float*)d_in[5];
    const float* q2 = (const float*)d_in[6];
    const float* k2 = (const float*)d_in[7];
    const float* b2 = (const float*)d_in[8];
    const int* eidx = (const int*)d_in[9];
    const int* etype = (const int*)d_in[10];
    const int* srcv = eidx;
    const int* dstv = eidx + N_EDGES;
    float* out = (float*)d_out;

    char* p = (char*)d_ws;
    auto alloc = [&](size_t bytes) -> void* {
        void* q = p;
        p += (bytes + 255) & ~(size_t)255;
        return q;
    };
    int* counts = (int*)alloc((size_t)NKEYS * 4);
    int* keyoff = (int*)alloc((size_t)(NKEYS + 1) * 4);
    int* cursor = (int*)alloc((size_t)NKEYS * 4);
    int* blocksum = (int*)alloc((size_t)SCAN_NBLK * 4);
    int* blockbase = (int*)alloc((size_t)SCAN_NBLK * 4);
    int* srcs = (int*)alloc((size_t)N_EDGES * 4);
    int* inv = (int*)alloc((size_t)N_EDGES * 4);
    ushort_t* emb_b = (ushort_t*)alloc((size_t)N_NODES * EMB * 2);
    ushort_t* wqkt1 = (ushort_t*)alloc((size_t)48 * 128 * 2);
    ushort_t* wagg1 = (ushort_t*)alloc((size_t)64 * 3072 * 2);
    ushort_t* wqkt2 = (ushort_t*)alloc((size_t)48 * 64 * 2);
    ushort_t* wagg2 = (ushort_t*)alloc((size_t)16 * 1536 * 2);
    float* qkd = (float*)alloc((size_t)N_NODES * 48 * 4);
    float* alpha = (float*)alloc((size_t)N_EDGES * 3 * 4);
    float* wcsr = (float*)alloc((size_t)N_EDGES * 3 * 4);
    ushort_t* x2 = (ushort_t*)alloc((size_t)N_NODES * 64 * 2);

    // ---- precomputes ----
    k_cvt<<<(N_NODES * EMB / 4 + 255) / 256, 256, 0, stream>>>(emb, emb_b, N_NODES * EMB / 4);
    k_wqk<128, 192><<<(48 * 128 + 255) / 256, 256, 0, stream>>>(w1, q1, k1, wqkt1);
    k_wqk<64, 48><<<(48 * 64 + 255) / 256, 256, 0, stream>>>(w2, q2, k2, wqkt2);
    k_wagg<128, 64><<<(64 * 3072 + 255) / 256, 256, 0, stream>>>(w1, wagg1);
    k_wagg<64, 16><<<(16 * 1536 + 255) / 256, 256, 0, stream>>>(w2, wagg2);

    // ---- CSR over (dst, rel) ----
    hipMemsetAsync(counts, 0, (size_t)NKEYS * 4, stream);
    k_count<<<(N_EDGES + 255) / 256, 256, 0, stream>>>(dstv, etype, counts);
    k_scanA<<<SCAN_NBLK, 256, 0, stream>>>(counts, keyoff, blocksum);
    k_scanB<<<1, 256, 0, stream>>>(blocksum, blockbase, keyoff);
    k_scanC<<<SCAN_NBLK, 256, 0, stream>>>(blockbase, keyoff, cursor);

    // ---- layer 1 ----
    k_mfma_gemm<128, 128, 48, 1, 3><<<dim3(313, 1), 256, 0, stream>>>(emb_b, wqkt1, qkd, N_NODES);
    k_scatter_alpha<<<(N_EDGES + 255) / 256, 256, 0, stream>>>(srcv, dstv, etype, qkd, cursor, srcs, inv, alpha);
    k_stats<<<N_NODES / 4, 256, 0, stream>>>(keyoff, alpha, wcsr);
    k_fused1<<<N_NODES / 16, 256, 0, stream>>>(keyoff, srcs, wcsr, emb_b, wagg1, b1, x2);

    // ---- layer 2 ----
    k_mfma_gemm<64, 64, 48, 1, 3><<<dim3(313, 1), 256, 0, stream>>>(x2, wqkt2, qkd, N_NODES);
    k_alpha2<<<(N_EDGES + 255) / 256, 256, 0, stream>>>(srcv, dstv, etype, inv, qkd, alpha);
    k_stats<<<N_NODES / 4, 256, 0, stream>>>(keyoff, alpha, wcsr);
    k_fused2<<<N_NODES / 16, 256, 0, stream>>>(keyoff, srcs, wcsr, x2, wagg2, b2, out);
}

// Round 7
// 275.203 us; speedup vs baseline: 2.5748x; 1.2961x over previous
//
#include <hip/hip_runtime.h>
#include <hip/hip_bf16.h>
#include <math.h>

#define N_NODES 20000
#define EMB 128
#define HID 64
#define RELS 8
#define CLS 16
#define N_EDGES 640000
#define NEG 0.2f
#define NKEYS (N_NODES * RELS)
#define SCAN_CHUNK 1024
#define SCAN_NBLK ((NKEYS + SCAN_CHUNK - 1) / SCAN_CHUNK)  // 157

typedef unsigned short ushort_t;
typedef __attribute__((ext_vector_type(8))) short bf16x8;
typedef __attribute__((ext_vector_type(8))) unsigned short ushort8_t;
typedef __attribute__((ext_vector_type(4))) unsigned short ushort4_t;
typedef __attribute__((ext_vector_type(4))) float f32x4;

__device__ __forceinline__ float b2f(ushort_t u) {
    return __uint_as_float(((unsigned int)u) << 16);
}
__device__ __forceinline__ ushort_t f2b(float f) {
    __hip_bfloat16 h = __float2bfloat16(f);
    return *reinterpret_cast<ushort_t*>(&h);
}

// ---------------- f32 -> bf16 conversion ----------------
__global__ __launch_bounds__(256) void k_cvt(const float* __restrict__ in, ushort_t* __restrict__ outp, int n4) {
    int i = blockIdx.x * blockDim.x + threadIdx.x;
    if (i >= n4) return;
    float4 v = *(const float4*)&in[(size_t)i * 4];
    ushort4 o;
    o.x = f2b(v.x); o.y = f2b(v.y); o.z = f2b(v.z); o.w = f2b(v.w);
    *(ushort4*)&outp[(size_t)i * 4] = o;
}

// ---------------- Wqk precompute ----------------
template <int D, int OUT>
__global__ __launch_bounds__(256) void k_wqk(const float* __restrict__ w, const float* __restrict__ q,
                                             const float* __restrict__ k, ushort_t* __restrict__ wqkt) {
    int tid = blockIdx.x * blockDim.x + threadIdx.x;
    if (tid >= 48 * D) return;
    int c = tid / D, i = tid % D;
    int r = c / 6, j = c % 6;
    const float* qk = (j < 3) ? q : k;
    int jj = (j < 3) ? j : j - 3;
    const float* wrow = w + ((size_t)r * D + i) * OUT;
    float s = 0.f;
    for (int o = 0; o < OUT; o++) s += wrow[o] * qk[o * 3 + jj];
    wqkt[(size_t)c * D + i] = f2b(s);
}

// ---------------- Wagg precompute: Bt[o][(r*3+h)*D + i] = w[r][i][h*OC + o] ----------------
template <int D, int OC>
__global__ __launch_bounds__(256) void k_wagg(const float* __restrict__ w, ushort_t* __restrict__ outp) {
    const int KT = RELS * 3 * D;
    int tid = blockIdx.x * blockDim.x + threadIdx.x;
    if (tid >= OC * KT) return;
    int o = tid / KT, kidx = tid % KT;
    int r = kidx / (3 * D), h = (kidx / D) % 3, i = kidx % D;
    float v = w[((size_t)r * D + i) * (3 * OC) + h * OC + o];
    outp[tid] = f2b(v);
}

// ---------------- CSR build over keys = dst*8 + rel ----------------
__global__ __launch_bounds__(256) void k_count(const int* __restrict__ dst, const int* __restrict__ et,
                                               int* __restrict__ counts) {
    int e = blockIdx.x * blockDim.x + threadIdx.x;
    if (e < N_EDGES) atomicAdd(&counts[dst[e] * 8 + et[e]], 1);
}

__global__ __launch_bounds__(256) void k_scanA(const int* __restrict__ counts, int* __restrict__ keyoff,
                                               int* __restrict__ blocksum) {
    __shared__ int part[256];
    int b = blockIdx.x, tid = threadIdx.x;
    int base = b * SCAN_CHUNK + tid * 4;
    int4 c = make_int4(0, 0, 0, 0);
    if (base + 3 < NKEYS) c = *(const int4*)&counts[base];
    else {
        if (base + 0 < NKEYS) c.x = counts[base + 0];
        if (base + 1 < NKEYS) c.y = counts[base + 1];
        if (base + 2 < NKEYS) c.z = counts[base + 2];
        if (base + 3 < NKEYS) c.w = counts[base + 3];
    }
    int s = c.x + c.y + c.z + c.w;
    part[tid] = s;
    __syncthreads();
    for (int off = 1; off < 256; off <<= 1) {
        int v = (tid >= off) ? part[tid - off] : 0;
        __syncthreads();
        part[tid] += v;
        __syncthreads();
    }
    int excl = part[tid] - s;
    int4 o;
    o.x = excl;
    o.y = excl + c.x;
    o.z = excl + c.x + c.y;
    o.w = excl + c.x + c.y + c.z;
    if (base + 3 < NKEYS) *(int4*)&keyoff[base] = o;
    else {
        if (base + 0 < NKEYS) keyoff[base + 0] = o.x;
        if (base + 1 < NKEYS) keyoff[base + 1] = o.y;
        if (base + 2 < NKEYS) keyoff[base + 2] = o.z;
        if (base + 3 < NKEYS) keyoff[base + 3] = o.w;
    }
    if (tid == 255) blocksum[b] = part[255];
}

__global__ __launch_bounds__(256) void k_scanB(int* __restrict__ blocksum, int* __restrict__ blockbase,
                                               int* __restrict__ keyoff) {
    __shared__ int part[256];
    int tid = threadIdx.x;
    int v0 = (tid < SCAN_NBLK) ? blocksum[tid] : 0;
    part[tid] = v0;
    __syncthreads();
    for (int off = 1; off < 256; off <<= 1) {
        int v = (tid >= off) ? part[tid - off] : 0;
        __syncthreads();
        part[tid] += v;
        __syncthreads();
    }
    if (tid < SCAN_NBLK) blockbase[tid] = part[tid] - v0;
    if (tid == 255) keyoff[NKEYS] = part[255];
}

__global__ __launch_bounds__(256) void k_scanC(const int* __restrict__ blockbase, int* __restrict__ keyoff,
                                               int* __restrict__ cursor) {
    int b = blockIdx.x, tid = threadIdx.x;
    int base = b * SCAN_CHUNK + tid * 4;
    int add = blockbase[b];
    if (base + 3 < NKEYS) {
        int4 v = *(const int4*)&keyoff[base];
        v.x += add; v.y += add; v.z += add; v.w += add;
        *(int4*)&keyoff[base] = v;
        *(int4*)&cursor[base] = v;
    } else {
        for (int j = 0; j < 4; j++) {
            if (base + j < NKEYS) {
                int v = keyoff[base + j] + add;
                keyoff[base + j] = v;
                cursor[base + j] = v;
            }
        }
    }
}

// ---------------- scatter srcs into CSR order ----------------
__global__ __launch_bounds__(256) void k_scatter(const int* __restrict__ src, const int* __restrict__ dst,
                                                 const int* __restrict__ et, int* __restrict__ cursor,
                                                 int* __restrict__ srcs) {
    int e = blockIdx.x * blockDim.x + threadIdx.x;
    if (e < N_EDGES) {
        int p = atomicAdd(&cursor[dst[e] * 8 + et[e]], 1);
        srcs[p] = src[e];
    }
}

// ---------------- direct-fragment MFMA GEMM (qkd projections) ----------------
template <int K, int KCH, int N, int MREP, int NREP>
__global__ __launch_bounds__(256) void k_mfma_gemm(const ushort_t* __restrict__ A, const ushort_t* __restrict__ Bt,
                                                   float* __restrict__ outp, int M) {
    const int wid = threadIdx.x >> 6;
    const int lane = threadIdx.x & 63;
    const int m0 = blockIdx.x * (4 * MREP * 16) + wid * (MREP * 16);
    const int kbase = blockIdx.y * KCH;
    const int l15 = lane & 15;
    const int kq = (lane >> 4) * 8;

    f32x4 acc[MREP][NREP] = {};
    for (int kk = kbase; kk < kbase + KCH; kk += 32) {
        bf16x8 a[MREP], b[NREP];
#pragma unroll
        for (int i = 0; i < MREP; i++) {
            int row = m0 + i * 16 + l15;
            row = row < M ? row : M - 1;
            a[i] = *(const bf16x8*)&A[(size_t)row * K + kk + kq];
        }
#pragma unroll
        for (int j = 0; j < NREP; j++) b[j] = *(const bf16x8*)&Bt[(size_t)(j * 16 + l15) * K + kk + kq];
#pragma unroll
        for (int i = 0; i < MREP; i++)
#pragma unroll
            for (int j = 0; j < NREP; j++)
                acc[i][j] = __builtin_amdgcn_mfma_f32_16x16x32_bf16(a[i], b[j], acc[i][j], 0, 0, 0);
    }
    float* op = outp + (size_t)blockIdx.y * M * N;
    const int r4 = (lane >> 4) * 4;
#pragma unroll
    for (int i = 0; i < MREP; i++) {
#pragma unroll
        for (int j = 0; j < NREP; j++) {
#pragma unroll
            for (int g = 0; g < 4; g++) {
                int row = m0 + i * 16 + r4 + g;
                if (row < M) op[(size_t)row * N + j * 16 + l15] = acc[i][j][g];
            }
        }
    }
}

// ---------------- per-edge alpha from qkd (on the fly) ----------------
__device__ __forceinline__ void edge_alpha(int s_idx, const int (&ko)[9], const int* __restrict__ srcs,
                                           const float* __restrict__ qkd, const float* __restrict__ qbase,
                                           float& a0, float& a1, float& a2) {
    int r = 0;
#pragma unroll
    for (int j = 1; j < 8; j++) r += (s_idx >= ko[j]) ? 1 : 0;
    int sv = srcs[s_idx];
    const float* kd = qkd + (size_t)sv * 48 + r * 6 + 3;
    const float* qd = qbase + r * 6;
    float t0 = qd[0] + kd[0], t1 = qd[1] + kd[1], t2 = qd[2] + kd[2];
    a0 = t0 > 0.f ? t0 : NEG * t0;
    a1 = t1 > 0.f ? t1 : NEG * t1;
    a2 = t2 > 0.f ? t2 : NEG * t2;
}

// ---------------- softmax stats (alpha fused in) -> normalized weights ----------------
__global__ __launch_bounds__(256) void k_stats(const int* __restrict__ keyoff, const int* __restrict__ srcs,
                                               const float* __restrict__ qkd, float* __restrict__ wcsr) {
    int node = blockIdx.x * 4 + (threadIdx.x >> 6);
    int lane = threadIdx.x & 63;
    int ko[9];
#pragma unroll
    for (int j = 0; j < 9; j++) ko[j] = keyoff[node * 8 + j];
    int beg = ko[0], end = ko[8], deg = end - beg;
    if (deg == 0) return;
    const float* qbase = qkd + (size_t)node * 48;

    if (deg <= 64) {
        float a0 = -INFINITY, a1 = -INFINITY, a2 = -INFINITY;
        if (lane < deg) edge_alpha(beg + lane, ko, srcs, qkd, qbase, a0, a1, a2);
        float m0 = a0, m1 = a1, m2 = a2;
#pragma unroll
        for (int off = 32; off >= 1; off >>= 1) {
            m0 = fmaxf(m0, __shfl_xor(m0, off));
            m1 = fmaxf(m1, __shfl_xor(m1, off));
            m2 = fmaxf(m2, __shfl_xor(m2, off));
        }
        float e0 = 0.f, e1 = 0.f, e2 = 0.f;
        if (lane < deg) {
            e0 = expf(a0 - m0);
            e1 = expf(a1 - m1);
            e2 = expf(a2 - m2);
        }
        float s0 = e0, s1 = e1, s2 = e2;
#pragma unroll
        for (int off = 32; off >= 1; off >>= 1) {
            s0 += __shfl_xor(s0, off);
            s1 += __shfl_xor(s1, off);
            s2 += __shfl_xor(s2, off);
        }
        float i0 = 1.f / (3.f * (s0 + 1e-16f));
        float i1 = 1.f / (3.f * (s1 + 1e-16f));
        float i2 = 1.f / (3.f * (s2 + 1e-16f));
        if (lane < deg) {
            size_t p = (size_t)(beg + lane) * 3;
            wcsr[p + 0] = e0 * i0;
            wcsr[p + 1] = e1 * i1;
            wcsr[p + 2] = e2 * i2;
        }
    } else {
        float m0 = -INFINITY, m1 = -INFINITY, m2 = -INFINITY;
        for (int i = beg + lane; i < end; i += 64) {
            float a0, a1, a2;
            edge_alpha(i, ko, srcs, qkd, qbase, a0, a1, a2);
            m0 = fmaxf(m0, a0); m1 = fmaxf(m1, a1); m2 = fmaxf(m2, a2);
        }
#pragma unroll
        for (int off = 32; off >= 1; off >>= 1) {
            m0 = fmaxf(m0, __shfl_xor(m0, off));
            m1 = fmaxf(m1, __shfl_xor(m1, off));
            m2 = fmaxf(m2, __shfl_xor(m2, off));
        }
        float s0 = 0.f, s1 = 0.f, s2 = 0.f;
        for (int i = beg + lane; i < end; i += 64) {
            float a0, a1, a2;
            edge_alpha(i, ko, srcs, qkd, qbase, a0, a1, a2);
            s0 += expf(a0 - m0); s1 += expf(a1 - m1); s2 += expf(a2 - m2);
        }
#pragma unroll
        for (int off = 32; off >= 1; off >>= 1) {
            s0 += __shfl_xor(s0, off);
            s1 += __shfl_xor(s1, off);
            s2 += __shfl_xor(s2, off);
        }
        float i0 = 1.f / (3.f * (s0 + 1e-16f));
        float i1 = 1.f / (3.f * (s1 + 1e-16f));
        float i2 = 1.f / (3.f * (s2 + 1e-16f));
        for (int i = beg + lane; i < end; i += 64) {
            float a0, a1, a2;
            edge_alpha(i, ko, srcs, qkd, qbase, a0, a1, a2);
            wcsr[(size_t)i * 3 + 0] = expf(a0 - m0) * i0;
            wcsr[(size_t)i * 3 + 1] = expf(a1 - m1) * i1;
            wcsr[(size_t)i * 3 + 2] = expf(a2 - m2) * i2;
        }
    }
}

// ---------------- FUSED layer 1 v3: quarter-wave gather + rel K-split ----------------
// grid (1250, 2): blockIdx.y picks rels [y*4, y*4+4). 16 nodes/block, 4 waves.
// Gather: quarter-wave (16 lanes) per node, lane = 8 cols (ushort8), no shuffles.
// PADK1=408 ushorts: row 816B (16B-aligned), 204 dwords %32=12 -> uniform 8/bank (conflict-free).
#define PADK1 408
__global__ __launch_bounds__(256) void k_fused1(const int* __restrict__ keyoff, const int* __restrict__ srcs,
                                                const float* __restrict__ wcsr, const ushort_t* __restrict__ x,
                                                const ushort_t* __restrict__ wagg, float* __restrict__ part) {
    __shared__ ushort_t lt[16][PADK1];  // 12.75 KB
    const int tid = threadIdx.x;
    const int w = tid >> 6, lane = tid & 63;
    const int q15 = lane & 15;
    const int l15 = lane & 15, kq = (lane >> 4) * 8;
    const int nbase = blockIdx.x * 16;
    const int RB = blockIdx.y * 4;
    const int mynode = w * 4 + (lane >> 4);  // 0..15 (quarter-wave id)
    const int gkey8 = (nbase + mynode) * 8;

    f32x4 acc = {};
    for (int rs = 0; rs < 4; rs++) {
        const int r = RB + rs;
        const int beg = keyoff[gkey8 + r], end = keyoff[gkey8 + r + 1];
        float a0[8] = {}, a1[8] = {}, a2[8] = {};
        for (int s = beg; s < end; s++) {
            int sv = srcs[s];
            float w0 = wcsr[(size_t)s * 3 + 0];
            float w1 = wcsr[(size_t)s * 3 + 1];
            float w2 = wcsr[(size_t)s * 3 + 2];
            ushort8_t xv = *(const ushort8_t*)&x[(size_t)sv * 128 + q15 * 8];
#pragma unroll
            for (int c = 0; c < 8; c++) {
                float f = b2f(xv[c]);
                a0[c] += w0 * f;
                a1[c] += w1 * f;
                a2[c] += w2 * f;
            }
        }
        ushort8_t o0, o1, o2;
#pragma unroll
        for (int c = 0; c < 8; c++) {
            o0[c] = f2b(a0[c]);
            o1[c] = f2b(a1[c]);
            o2[c] = f2b(a2[c]);
        }
        *(ushort8_t*)&lt[mynode][0 * 128 + q15 * 8] = o0;
        *(ushort8_t*)&lt[mynode][1 * 128 + q15 * 8] = o1;
        *(ushort8_t*)&lt[mynode][2 * 128 + q15 * 8] = o2;
        __syncthreads();
        // MFMA: wave w -> output cols [w*16, w*16+16), K=384
#pragma unroll
        for (int ks = 0; ks < 12; ks++) {
            bf16x8 av = *(const bf16x8*)&lt[l15][ks * 32 + kq];
            bf16x8 bv = *(const bf16x8*)&wagg[(size_t)(w * 16 + l15) * 3072 + r * 384 + ks * 32 + kq];
            acc = __builtin_amdgcn_mfma_f32_16x16x32_bf16(av, bv, acc, 0, 0, 0);
        }
        __syncthreads();
    }
    float* op = part + (size_t)blockIdx.y * N_NODES * 64;
    const int r4 = (lane >> 4) * 4;
#pragma unroll
    for (int g = 0; g < 4; g++) {
        int row = nbase + r4 + g;
        op[(size_t)row * 64 + w * 16 + l15] = acc[g];
    }
}

// ---------------- FUSED layer 2 v3: wave owns one relation ----------------
// grid (1250, 2). PADK2=208: row 416B (16B aligned), 104 dwords %32=8 -> uniform 8/bank.
#define PADK2 208
__global__ __launch_bounds__(256) void k_fused2(const int* __restrict__ keyoff, const int* __restrict__ srcs,
                                                const float* __restrict__ wcsr, const ushort_t* __restrict__ x2in,
                                                const ushort_t* __restrict__ wagg, float* __restrict__ part) {
    __shared__ ushort_t lt2[4][16][PADK2];  // 26 KB (wave-private tiles); red aliases after use
    const int tid = threadIdx.x;
    const int w = tid >> 6, lane = tid & 63;
    const int q = lane >> 4, q15 = lane & 15;
    const int l15 = lane & 15, kq = (lane >> 4) * 8;
    const int nbase = blockIdx.x * 16;
    const int r = blockIdx.y * 4 + w;

    f32x4 acc = {};
#pragma unroll 1
    for (int ns = 0; ns < 4; ns++) {
        const int n = ns * 4 + q;
        const int key = (nbase + n) * 8 + r;
        const int beg = keyoff[key], end = keyoff[key + 1];
        float a0[4] = {}, a1[4] = {}, a2[4] = {};
        for (int s = beg; s < end; s++) {
            int sv = srcs[s];
            float w0 = wcsr[(size_t)s * 3 + 0];
            float w1 = wcsr[(size_t)s * 3 + 1];
            float w2 = wcsr[(size_t)s * 3 + 2];
            ushort4_t xv = *(const ushort4_t*)&x2in[(size_t)sv * 64 + q15 * 4];
#pragma unroll
            for (int c = 0; c < 4; c++) {
                float f = b2f(xv[c]);
                a0[c] += w0 * f;
                a1[c] += w1 * f;
                a2[c] += w2 * f;
            }
        }
        ushort4_t o0, o1, o2;
#pragma unroll
        for (int c = 0; c < 4; c++) {
            o0[c] = f2b(a0[c]);
            o1[c] = f2b(a1[c]);
            o2[c] = f2b(a2[c]);
        }
        *(ushort4_t*)&lt2[w][n][0 * 64 + q15 * 4] = o0;
        *(ushort4_t*)&lt2[w][n][1 * 64 + q15 * 4] = o1;
        *(ushort4_t*)&lt2[w][n][2 * 64 + q15 * 4] = o2;
    }
    // wave-private MFMA (no barrier needed), K=192
#pragma unroll
    for (int ks = 0; ks < 6; ks++) {
        bf16x8 av = *(const bf16x8*)&lt2[w][l15][ks * 32 + kq];
        bf16x8 bv = *(const bf16x8*)&wagg[(size_t)l15 * 1536 + r * 192 + ks * 32 + kq];
        acc = __builtin_amdgcn_mfma_f32_16x16x32_bf16(av, bv, acc, 0, 0, 0);
    }
    __syncthreads();  // all waves done with lt2 -> safe to alias as red
    float* red = (float*)&lt2[0][0][0];  // [4][16][17]
    const int r4 = (lane >> 4) * 4;
#pragma unroll
    for (int g = 0; g < 4; g++) red[(w * 16 + r4 + g) * 17 + l15] = acc[g];
    __syncthreads();
    int row = tid >> 4, col = tid & 15;
    float v = red[(0 * 16 + row) * 17 + col] + red[(1 * 16 + row) * 17 + col] +
              red[(2 * 16 + row) * 17 + col] + red[(3 * 16 + row) * 17 + col];
    part[(size_t)blockIdx.y * N_NODES * 16 + (size_t)(nbase + row) * 16 + col] = v;
}

// ---------------- partials reduce + bias + relu -> bf16 x2 ----------------
__global__ __launch_bounds__(256) void k_reduce1(const float* __restrict__ part, const float* __restrict__ bias,
                                                 ushort_t* __restrict__ x2) {
    int idx = blockIdx.x * blockDim.x + threadIdx.x;
    const int MN = N_NODES * 64;
    if (idx >= MN) return;
    float s = part[idx] + part[idx + MN] + bias[idx & 63];
    x2[idx] = f2b(s > 0.f ? s : 0.f);
}

// ---------------- partials reduce + bias + sigmoid -> out f32 ----------------
__global__ __launch_bounds__(256) void k_reduce2(const float* __restrict__ part, const float* __restrict__ bias,
                                                 float* __restrict__ outp) {
    int idx = blockIdx.x * blockDim.x + threadIdx.x;
    const int MN = N_NODES * 16;
    if (idx >= MN) return;
    float s = part[idx] + part[idx + MN] + bias[idx & 15];
    outp[idx] = 1.f / (1.f + expf(-s));
}

extern "C" void kernel_launch(void* const* d_in, const int* in_sizes, int n_in, void* d_out, int out_size,
                              void* d_ws, size_t ws_size, hipStream_t stream) {
    const float* emb = (const float*)d_in[0];
    const float* w1 = (const float*)d_in[1];
    const float* q1 = (const float*)d_in[2];
    const float* k1 = (const float*)d_in[3];
    const float* b1 = (const float*)d_in[4];
    const float* w2 = (const float*)d_in[5];
    const float* q2 = (const float*)d_in[6];
    const float* k2 = (const float*)d_in[7];
    const float* b2 = (const float*)d_in[8];
    const int* eidx = (const int*)d_in[9];
    const int* etype = (const int*)d_in[10];
    const int* srcv = eidx;
    const int* dstv = eidx + N_EDGES;
    float* out = (float*)d_out;

    char* p = (char*)d_ws;
    auto alloc = [&](size_t bytes) -> void* {
        void* q = p;
        p += (bytes + 255) & ~(size_t)255;
        return q;
    };
    int* counts = (int*)alloc((size_t)NKEYS * 4);
    int* keyoff = (int*)alloc((size_t)(NKEYS + 1) * 4);
    int* cursor = (int*)alloc((size_t)NKEYS * 4);
    int* blocksum = (int*)alloc((size_t)SCAN_NBLK * 4);
    int* blockbase = (int*)alloc((size_t)SCAN_NBLK * 4);
    int* srcs = (int*)alloc((size_t)N_EDGES * 4);
    ushort_t* emb_b = (ushort_t*)alloc((size_t)N_NODES * EMB * 2);
    ushort_t* wqkt1 = (ushort_t*)alloc((size_t)48 * 128 * 2);
    ushort_t* wagg1 = (ushort_t*)alloc((size_t)64 * 3072 * 2);
    ushort_t* wqkt2 = (ushort_t*)alloc((size_t)48 * 64 * 2);
    ushort_t* wagg2 = (ushort_t*)alloc((size_t)16 * 1536 * 2);
    float* qkd = (float*)alloc((size_t)N_NODES * 48 * 4);
    float* wcsr = (float*)alloc((size_t)N_EDGES * 3 * 4);
    ushort_t* x2 = (ushort_t*)alloc((size_t)N_NODES * 64 * 2);
    float* partials = (float*)alloc((size_t)2 * N_NODES * 64 * 4);

    // ---- precomputes ----
    k_cvt<<<(N_NODES * EMB / 4 + 255) / 256, 256, 0, stream>>>(emb, emb_b, N_NODES * EMB / 4);
    k_wqk<128, 192><<<(48 * 128 + 255) / 256, 256, 0, stream>>>(w1, q1, k1, wqkt1);
    k_wqk<64, 48><<<(48 * 64 + 255) / 256, 256, 0, stream>>>(w2, q2, k2, wqkt2);
    k_wagg<128, 64><<<(64 * 3072 + 255) / 256, 256, 0, stream>>>(w1, wagg1);
    k_wagg<64, 16><<<(16 * 1536 + 255) / 256, 256, 0, stream>>>(w2, wagg2);

    // ---- CSR over (dst, rel) ----
    hipMemsetAsync(counts, 0, (size_t)NKEYS * 4, stream);
    k_count<<<(N_EDGES + 255) / 256, 256, 0, stream>>>(dstv, etype, counts);
    k_scanA<<<SCAN_NBLK, 256, 0, stream>>>(counts, keyoff, blocksum);
    k_scanB<<<1, 256, 0, stream>>>(blocksum, blockbase, keyoff);
    k_scanC<<<SCAN_NBLK, 256, 0, stream>>>(blockbase, keyoff, cursor);
    k_scatter<<<(N_EDGES + 255) / 256, 256, 0, stream>>>(srcv, dstv, etype, cursor, srcs);

    // ---- layer 1 ----
    k_mfma_gemm<128, 128, 48, 1, 3><<<dim3(313, 1), 256, 0, stream>>>(emb_b, wqkt1, qkd, N_NODES);
    k_stats<<<N_NODES / 4, 256, 0, stream>>>(keyoff, srcs, qkd, wcsr);
    k_fused1<<<dim3(N_NODES / 16, 2), 256, 0, stream>>>(keyoff, srcs, wcsr, emb_b, wagg1, partials);
    k_reduce1<<<(N_NODES * 64 + 255) / 256, 256, 0, stream>>>(partials, b1, x2);

    // ---- layer 2 ----
    k_mfma_gemm<64, 64, 48, 1, 3><<<dim3(313, 1), 256, 0, stream>>>(x2, wqkt2, qkd, N_NODES);
    k_stats<<<N_NODES / 4, 256, 0, stream>>>(keyoff, srcs, qkd, wcsr);
    k_fused2<<<dim3(N_NODES / 16, 2), 256, 0, stream>>>(keyoff, srcs, wcsr, x2, wagg2, partials);
    k_reduce2<<<(N_NODES * 16 + 255) / 256, 256, 0, stream>>>(partials, b2, out);
}